// Round 11
// baseline (2395.822 us; speedup 1.0000x reference)
//
#include <hip/hip_runtime.h>
#include <math.h>

// Hierarchical RNN — round 19: base = round-17 (verified 2174us; r18's 32-col
// split reverted — 64x64x3 step block is a local optimum). Layer-0's xe·Wih
// phase hoisted into the MODE-3 fragment GEMM (verified mechanism from layer 1),
// so BOTH layers now use the single-phase gru_step_h (8 chunks for D=512,
// half the barriers/staging of the old 2-phase gru_step). gi0 computed in
// groups of gsz steps to bound workspace.

#define NB     10272
#define MP     10368
#define ENC_   321
#define SEQ_   720
#define PRED_  96
#define BATCH_ 32

typedef long long i64;
typedef unsigned short u16;
typedef unsigned int u32;
using bf16x8 = __attribute__((ext_vector_type(8))) short;
using f32x4  = __attribute__((ext_vector_type(4))) float;
using u16x4  = __attribute__((ext_vector_type(4))) unsigned short;

#define AS1 __attribute__((address_space(1)))
#define AS3 __attribute__((address_space(3)))
#define GLOAD16(g, l) __builtin_amdgcn_global_load_lds((const AS1 void*)(g), (AS3 void*)(l), 16, 0, 0)
#define MFMA16(a, b, c) __builtin_amdgcn_mfma_f32_16x16x32_bf16(a, b, c, 0, 0, 0)

__device__ __forceinline__ float bf2f(u16 u) {
    union { u32 i; float f; } v; v.i = ((u32)u) << 16; return v.f;
}
__device__ __forceinline__ u16 f2bf(float f) {
    union { float f; u32 i; } v; v.f = f;
    return (u16)((v.i + 0x7fff + ((v.i >> 16) & 1)) >> 16);
}
__device__ __forceinline__ float sigf(float x) {
    x = fminf(fmaxf(x, -30.f), 30.f);
    return 1.f / (1.f + __expf(-x));
}
__device__ __forceinline__ float tanhfast(float x) {
    x = fminf(fmaxf(x, -15.f), 15.f);
    float e = __expf(2.f * x);
    return (e - 1.f) / (e + 1.f);
}
// XCD-aware flat-grid swizzle for the big GEMMs
__device__ __forceinline__ void swz(int idx, int NXT, int NYT, int& mt, int& nt) {
    int per = NYT * 8;
    int grp = idx / per;
    int base = grp * 8;
    int mg = NXT - base; if (mg > 8) mg = 8;
    int rem = idx - grp * per;
    mt = base + rem % mg;
    nt = rem / mg;
}

// ---------------------------------------------------------------- small utils
__global__ __launch_bounds__(256) void zero_bf(u16* __restrict__ b, i64 n) {
    i64 i = (i64)blockIdx.x * 256 + threadIdx.x;
    i64 n2 = n >> 1;
    if (i < n2) ((u32*)b)[i] = 0;
}

__global__ __launch_bounds__(256) void convert_pad(const float* __restrict__ src,
                                                   u16* __restrict__ dst,
                                                   int R, int C, int Rp, int Cp) {
    i64 idx = (i64)blockIdx.x * 256 + threadIdx.x;
    i64 total = (i64)Rp * Cp;
    if (idx >= total) return;
    int r = (int)(idx / Cp);
    int c = (int)(idx - (i64)r * Cp);
    dst[idx] = (r < R && c < C) ? f2bf(src[(i64)r * C + c]) : (u16)0;
}

__global__ __launch_bounds__(256) void seg_gather_bf(const float* __restrict__ x,
                                                     u16* __restrict__ dst,
                                                     int t0, int T, int s, int Kp) {
    i64 idx = (i64)blockIdx.x * 256 + threadIdx.x;
    i64 per_t = (i64)MP * Kp;
    i64 total = (i64)T * per_t;
    if (idx >= total) return;
    int t = (int)(idx / per_t);
    i64 rem = idx - (i64)t * per_t;
    int j = (int)(rem / MP);
    int n = (int)(rem - (i64)j * MP);
    float v = 0.f;
    if (n < NB && j < s) {
        int b = n / ENC_, e = n - b * ENC_;
        const float* xb = x + (i64)b * SEQ_ * ENC_ + e;
        v = xb[(i64)((t0 + t) * s + j) * ENC_] - xb[(i64)(SEQ_ - 1) * ENC_];
    }
    dst[((i64)t * MP + n) * Kp + j] = f2bf(v);
}

__global__ __launch_bounds__(256) void pmat_fill_bf(const float* __restrict__ pos,
                                                    const float* __restrict__ chan,
                                                    u16* __restrict__ dst,
                                                    int S, int d, int Rp) {
    i64 idx = (i64)blockIdx.x * 256 + threadIdx.x;
    i64 total = (i64)Rp * d;
    if (idx >= total) return;
    int row = (int)(idx / d);
    int c = (int)(idx - (i64)row * d);
    float v = 0.f;
    if (row < ENC_ * S) {
        int e = row / S, sy = row - e * S;
        int half = d >> 1;
        v = (c < half) ? pos[sy * half + c] : chan[e * half + (c - half)];
    }
    dst[idx] = f2bf(v);
}

__global__ __launch_bounds__(256) void out_kernel(const float* __restrict__ x,
                                                  const float* __restrict__ y0,
                                                  const float* __restrict__ y1,
                                                  float* __restrict__ out) {
    int idx = blockIdx.x * 256 + threadIdx.x;
    const int total = BATCH_ * PRED_ * ENC_;
    if (idx >= total) return;
    int b = idx / (PRED_ * ENC_);
    int r = idx - b * (PRED_ * ENC_);
    int p = r / ENC_;
    int e = r - p * ENC_;
    int n = b * ENC_ + e;
    float sl = x[(i64)b * SEQ_ * ENC_ + (i64)(SEQ_ - 1) * ENC_ + e];
    out[idx] = sl + 0.5f * (y0[(i64)n * PRED_ + p] + y1[(i64)n * PRED_ + p]);
}

// ------------------------------------------------- bf16 MFMA NT GEMM 128x128xK
// MODE: 0 fp32 natural, 1 bf16 natural, 2 bf16+relu, 3 bf16 fragment layout
template<int MODE>
__global__ __launch_bounds__(256) void gemm_bf16mfma(const u16* __restrict__ A,
                                                     const u16* __restrict__ B,
                                                     const float* __restrict__ bias,
                                                     void* __restrict__ Cp,
                                                     int K, int Mstore, int Nstore,
                                                     int ldc, int NXT, int NYT) {
    __shared__ u16 smA[128 * 64];
    __shared__ u16 smB[128 * 64];
    const int tid = threadIdx.x;
    const int w = tid >> 6, l = tid & 63;
    int mt, nt; swz(blockIdx.x, NXT, NYT, mt, nt);
    const int m0 = mt * 128, n0 = nt * 128;
    const int srow = (l >> 3) & 7, pch = l & 7;
    const int cch = pch ^ srow;
    const u16* ga[4]; const u16* gb[4];
#pragma unroll
    for (int r = 0; r < 4; ++r) {
        int seg = r * 4 + w;
        ga[r] = A + (i64)(m0 + seg * 8 + srow) * K + cch * 8;
        gb[r] = B + (i64)(n0 + seg * 8 + srow) * K + cch * 8;
    }
    f32x4 acc[4][4] = {};
    const int lr = l & 15, lg = l >> 4;
    const int wm = (w >> 1) * 64, wn = (w & 1) * 64;
    for (int kk = 0; kk < K; kk += 64) {
#pragma unroll
        for (int r = 0; r < 4; ++r) { GLOAD16(ga[r], smA + (r * 4 + w) * 512); ga[r] += 64; }
#pragma unroll
        for (int r = 0; r < 4; ++r) { GLOAD16(gb[r], smB + (r * 4 + w) * 512); gb[r] += 64; }
        __syncthreads();
#pragma unroll
        for (int s = 0; s < 2; ++s) {
            const int ph = ((s * 4 + lg) ^ (lr & 7)) * 8;
            bf16x8 av[4], bv[4];
#pragma unroll
            for (int i = 0; i < 4; ++i)
                av[i] = *(const bf16x8*)(smA + (wm + i * 16 + lr) * 64 + ph);
#pragma unroll
            for (int j = 0; j < 4; ++j)
                bv[j] = *(const bf16x8*)(smB + (wn + j * 16 + lr) * 64 + ph);
#pragma unroll
            for (int i = 0; i < 4; ++i)
#pragma unroll
                for (int j = 0; j < 4; ++j)
                    acc[i][j] = MFMA16(av[i], bv[j], acc[i][j]);
        }
        __syncthreads();
    }
    if (MODE == 3) {
        // fragment-layout bf16 store: tile (row/16, col/16), elem lane*4+reg.
        const int NCTG = ldc >> 4;
#pragma unroll
        for (int i = 0; i < 4; ++i) {
            int mt16 = (m0 + wm + i * 16) >> 4;
#pragma unroll
            for (int j = 0; j < 4; ++j) {
                int cb = n0 + wn + j * 16;
                if (cb >= Nstore) continue;
                float bs = bias[cb + lr];
                u16x4 sv;
#pragma unroll
                for (int r = 0; r < 4; ++r) sv[r] = f2bf(acc[i][j][r] + bs);
                *(u16x4*)((u16*)Cp + ((i64)mt16 * NCTG + (cb >> 4)) * 256 + l * 4) = sv;
            }
        }
        return;
    }
#pragma unroll
    for (int i = 0; i < 4; ++i) {
        int mbase = m0 + wm + i * 16 + 4 * lg;
#pragma unroll
        for (int j = 0; j < 4; ++j) {
            int c = n0 + wn + j * 16 + lr;
            if (c >= Nstore) continue;
            float bs = bias[c];
#pragma unroll
            for (int r = 0; r < 4; ++r) {
                int mm = mbase + r;
                if (mm < Mstore) {
                    float v = acc[i][j][r] + bs;
                    if (MODE == 2) v = fmaxf(v, 0.f);
                    if (MODE == 0) ((float*)Cp)[(i64)mm * ldc + c] = v;
                    else           ((u16*)Cp)[(i64)mm * ldc + c] = f2bf(v);
                }
            }
        }
    }
}

// ---------------- h-only encoder step (both layers): gh = h·Whh; gi from
// precomputed fragment-layout buffer, prefetched under the last MFMA chunk.
// h_old from LDS side copy of the kk==c0 A-chunk. 64x64x3 per block;
// grid (162, D/64).
template<int D>
__global__ __launch_bounds__(256, 3) void gru_step_h(const u16* __restrict__ gi,
                                                     const u16* __restrict__ hsrc,
                                                     const u16* __restrict__ Whh,
                                                     const float* __restrict__ bhh,
                                                     u16* __restrict__ hdst) {
    constexpr int NCT = D / 16;
    constexpr int NCTG = 3 * D / 16;   // gi col tiles
    __shared__ u16 smA[64 * 64];
    __shared__ u16 smB[3 * 64 * 64];
    __shared__ u16 smH[64 * 64];
    const int tid = threadIdx.x;
    const int w = tid >> 6, l = tid & 63;
    const int m0 = blockIdx.x * 64;
    const int c0 = blockIdx.y * 64;
    const int srow = (l >> 3) & 7, pch = l & 7;
    const int cch = pch ^ srow;
    const int lr = l & 15, lg = l >> 4;
    f32x4 aR[4] = {}, aZ[4] = {}, aNH[4] = {};
    const u16* ga[2]; const u16* gb[6];
#pragma unroll
    for (int r = 0; r < 2; ++r)
        ga[r] = hsrc + (i64)(m0 + (r * 4 + w) * 8 + srow) * D + cch * 8;
#pragma unroll
    for (int q = 0; q < 6; ++q) {
        int gs = q * 4 + w;
        int g = gs >> 3, sp = gs & 7;
        gb[q] = Whh + (i64)(g * D + c0 + sp * 8 + srow) * D + cch * 8;
    }
    const int Trow = (m0 >> 4) + w;
    const i64 gbase = (i64)Trow * NCTG * 256 + l * 4;
    u16x4 g0[4], g1[4], g2[4];
    for (int kk = 0; kk < D; kk += 64) {
#pragma unroll
        for (int r = 0; r < 2; ++r) GLOAD16(ga[r], smA + (r * 4 + w) * 512);
        if (kk == c0) {
#pragma unroll
            for (int r = 0; r < 2; ++r) GLOAD16(ga[r], smH + (r * 4 + w) * 512);
        }
#pragma unroll
        for (int r = 0; r < 2; ++r) ga[r] += 64;
#pragma unroll
        for (int q = 0; q < 6; ++q) { GLOAD16(gb[q], smB + (q * 4 + w) * 512); gb[q] += 64; }
        __syncthreads();
        if (kk == D - 64) {
            // prefetch gi fragments; latency hides under this chunk's MFMAs
#pragma unroll
            for (int j = 0; j < 4; ++j) {
                const int ct = (c0 >> 4) + j;
                g0[j] = *(const u16x4*)(gi + gbase + (i64)(0 * NCT + ct) * 256);
                g1[j] = *(const u16x4*)(gi + gbase + (i64)(1 * NCT + ct) * 256);
                g2[j] = *(const u16x4*)(gi + gbase + (i64)(2 * NCT + ct) * 256);
            }
        }
#pragma unroll
        for (int s = 0; s < 2; ++s) {
            const int phs = ((s * 4 + lg) ^ (lr & 7)) * 8;
            bf16x8 av = *(const bf16x8*)(smA + (w * 16 + lr) * 64 + phs);
#pragma unroll
            for (int j = 0; j < 4; ++j) {
                bf16x8 b0 = *(const bf16x8*)(smB + 0 * 4096 + (j * 16 + lr) * 64 + phs);
                bf16x8 b1 = *(const bf16x8*)(smB + 1 * 4096 + (j * 16 + lr) * 64 + phs);
                bf16x8 b2 = *(const bf16x8*)(smB + 2 * 4096 + (j * 16 + lr) * 64 + phs);
                aR[j] = MFMA16(av, b0, aR[j]);
                aZ[j] = MFMA16(av, b1, aZ[j]);
                aNH[j] = MFMA16(av, b2, aNH[j]);
            }
        }
        __syncthreads();
    }
    // epilogue: gi fragments already in registers; h_old from smH
    const int rowb = m0 + w * 16 + 4 * lg;
#pragma unroll
    for (int j = 0; j < 4; ++j) {
        const int cc = c0 + j * 16 + lr;
        float bR = bhh[cc];
        float bZ = bhh[D + cc];
        float bNH = bhh[2 * D + cc];
#pragma unroll
        for (int r = 0; r < 4; ++r) {
            const int lrow = w * 16 + 4 * lg + r;
            const int lcol = j * 16 + lr;
            float ho = bf2f(smH[lrow * 64 + ((((lcol >> 3)) ^ (lrow & 7)) << 3) + (lcol & 7)]);
            float rr = sigf(bf2f(g0[j][r]) + aR[j][r] + bR);
            float zz = sigf(bf2f(g1[j][r]) + aZ[j][r] + bZ);
            float nn = tanhfast(bf2f(g2[j][r]) + rr * (aNH[j][r] + bNH));
            hdst[(i64)(rowb + r) * D + cc] = f2bf((1.f - zz) * nn + zz * ho);
        }
    }
}

// ---------------------------------------- decoder: fused gh-GEMM + GRU (S>0)
// h_old read directly from the bf16 mirror (= Asrc), no fp32 hfrag.
template<int D, int S>
__global__ __launch_bounds__(256) void gru_dec(const u16* __restrict__ Asrc,
                                               const u16* __restrict__ Whh,
                                               const float* __restrict__ bhh,
                                               const u16* __restrict__ gi,
                                               u16* __restrict__ hy) {
    constexpr int NYT = D / 64;
    __shared__ u16 smA[128 * 64];
    __shared__ u16 smB[3 * 64 * 64];
    const int tid = threadIdx.x;
    const int w = tid >> 6, l = tid & 63;
    int mt, nt; swz(blockIdx.x, 81, NYT, mt, nt);
    const int m0 = mt * 128;
    const int c0 = nt * 64;
    const int srow = (l >> 3) & 7, pch = l & 7;
    const int cch = pch ^ srow;
    const u16* ga[4]; const u16* gb[6];
#pragma unroll
    for (int r = 0; r < 4; ++r)
        ga[r] = Asrc + (i64)(m0 + (r * 4 + w) * 8 + srow) * D + cch * 8;
#pragma unroll
    for (int q = 0; q < 6; ++q) {
        int gs = q * 4 + w;
        int g = gs >> 3, sp = gs & 7;
        gb[q] = Whh + (i64)(g * D + c0 + sp * 8 + srow) * D + cch * 8;
    }
    f32x4 acc[3][4][2] = {};
    const int lr = l & 15, lg = l >> 4;
    const int wm = (w >> 1) * 64, wc = (w & 1) * 32;
    for (int kk = 0; kk < D; kk += 64) {
#pragma unroll
        for (int r = 0; r < 4; ++r) { GLOAD16(ga[r], smA + (r * 4 + w) * 512); ga[r] += 64; }
#pragma unroll
        for (int q = 0; q < 6; ++q) { GLOAD16(gb[q], smB + (q * 4 + w) * 512); gb[q] += 64; }
        __syncthreads();
#pragma unroll
        for (int s = 0; s < 2; ++s) {
            const int ph = ((s * 4 + lg) ^ (lr & 7)) * 8;
            bf16x8 av[4], bv[3][2];
#pragma unroll
            for (int i = 0; i < 4; ++i)
                av[i] = *(const bf16x8*)(smA + (wm + i * 16 + lr) * 64 + ph);
#pragma unroll
            for (int g = 0; g < 3; ++g)
#pragma unroll
                for (int j = 0; j < 2; ++j)
                    bv[g][j] = *(const bf16x8*)(smB + g * 4096 + (wc + j * 16 + lr) * 64 + ph);
#pragma unroll
            for (int g = 0; g < 3; ++g)
#pragma unroll
                for (int i = 0; i < 4; ++i)
#pragma unroll
                    for (int j = 0; j < 2; ++j)
                        acc[g][i][j] = MFMA16(av[i], bv[g][j], acc[g][i][j]);
        }
        __syncthreads();
    }
#pragma unroll
    for (int i = 0; i < 4; ++i) {
        const int rowb = m0 + wm + 16 * i + 4 * lg;
        int e0 = rowb % ENC_;
#pragma unroll
        for (int j = 0; j < 2; ++j) {
            const int cc = c0 + wc + 16 * j + lr;
            float b0 = bhh[cc], b1 = bhh[D + cc], b2 = bhh[2 * D + cc];
#pragma unroll
            for (int r = 0; r < 4; ++r) {
                int mm = rowb + r;
                if (mm >= NB) continue;
                int e = e0 + r; if (e >= ENC_) e -= ENC_;
                float ho = bf2f(Asrc[(i64)mm * D + cc]);
                float hr = acc[0][i][j][r] + b0;
                float hz = acc[1][i][j][r] + b1;
                float hn2 = acc[2][i][j][r] + b2;
#pragma unroll
                for (int sy = 0; sy < S; ++sy) {
                    i64 gib = (i64)(e * S + sy) * 3 * D + cc;
                    float rr = sigf(bf2f(gi[gib]) + hr);
                    float zz = sigf(bf2f(gi[gib + D]) + hz);
                    float nn = tanhfast(bf2f(gi[gib + 2 * D]) + rr * hn2);
                    hy[((i64)mm * S + sy) * D + cc] = f2bf((1.f - zz) * nn + zz * ho);
                }
            }
        }
    }
}

// ---------------------------------------------------------------- host
extern "C" void kernel_launch(void* const* d_in, const int* in_sizes, int n_in,
                              void* d_out, int out_size, void* d_ws, size_t ws_size,
                              hipStream_t stream) {
    const float* x      = (const float*)d_in[0];
    const float* W_emb0 = (const float*)d_in[1];
    const float* b_emb0 = (const float*)d_in[2];
    const float* Wih0   = (const float*)d_in[3];
    const float* Whh0   = (const float*)d_in[4];
    const float* bih0   = (const float*)d_in[5];
    const float* bhh0   = (const float*)d_in[6];
    const float* Wpred0 = (const float*)d_in[7];
    const float* bpred0 = (const float*)d_in[8];
    const float* pos0   = (const float*)d_in[9];
    const float* chan0  = (const float*)d_in[10];
    const float* W_emb1 = (const float*)d_in[11];
    const float* b_emb1 = (const float*)d_in[12];
    const float* Wih1   = (const float*)d_in[13];
    const float* Whh1   = (const float*)d_in[14];
    const float* bih1   = (const float*)d_in[15];
    const float* bhh1   = (const float*)d_in[16];
    const float* Wpred1 = (const float*)d_in[17];
    const float* bpred1 = (const float*)d_in[18];
    const float* pos1   = (const float*)d_in[19];
    const float* chan1  = (const float*)d_in[20];
    float* out = (float*)d_out;

    i64 off = 0;
    char* base = (char*)d_ws;
    auto alloc = [&](i64 bytes) -> void* {
        void* p = base + off; off += (bytes + 255) & ~(i64)255; return p;
    };
    u16*   f_mirA  = (u16*)  alloc((i64)MP * 512 * 2);   // ping-pong mirrors
    u16*   f_mirB  = (u16*)  alloc((i64)MP * 512 * 2);
    u16*   wih0b   = (u16*)  alloc((i64)1536 * 512 * 2);
    u16*   whh0b   = (u16*)  alloc((i64)1536 * 512 * 2);
    u16*   wih1b   = (u16*)  alloc((i64)768 * 256 * 2);
    u16*   whh1b   = (u16*)  alloc((i64)768 * 256 * 2);
    u16*   we0b    = (u16*)  alloc((i64)512 * 64 * 2);
    u16*   we1b    = (u16*)  alloc((i64)256 * 64 * 2);
    u16*   wp0b    = (u16*)  alloc((i64)128 * 512 * 2);
    u16*   wp1b    = (u16*)  alloc((i64)128 * 256 * 2);
    u16*   f_pm0   = (u16*)  alloc((i64)768 * 512 * 2);
    u16*   f_pm1   = (u16*)  alloc((i64)1408 * 256 * 2);
    u16*   f_gidec = (u16*)  alloc((i64)768 * 1536 * 2);
    u16*   f_hy    = (u16*)  alloc((i64)4 * NB * 256 * 2); // decoder hy (max of layers)
    float* f_y0    = (float*)alloc((i64)NB * 96 * 4);
    float* f_y1    = (float*)alloc((i64)NB * 96 * 4);
    i64 fixed = off;

    // shared region R (phase-exclusive):
    //   layer-0 phase: seg0 | xe0 | gi0 (groups of gsz steps)
    //   layer-1 phase: seg1 | xe1 | gi1 (fragment layout)
    char* R = base + fixed;
    i64 a1 = (((i64)4 * MP * 64 * 2) + 255) & ~(i64)255;    // seg1
    i64 a2 = (((i64)4 * MP * 256 * 2) + 255) & ~(i64)255;   // xe1
    i64 a3 = (i64)4 * MP * 768 * 2;                         // gi1
    i64 R1 = a1 + a2 + a3;
    u16* f_seg1 = (u16*)R;
    u16* f_xe1  = (u16*)(R + a1);
    u16* f_gi1  = (u16*)(R + a1 + a2);
    int gsz = 1;
    {
        const int cand[4] = {5, 3, 2, 1};
        for (int ii = 0; ii < 4; ++ii) {
            i64 need = (i64)cand[ii] * MP * (64 + 512 + 1536) * 2 + 3 * 256;
            i64 tot = fixed + (need > R1 ? need : R1);
            if (tot <= (i64)ws_size) { gsz = cand[ii]; break; }
        }
    }
    u16* f_seg0 = (u16*)R;
    i64 s0a = (((i64)gsz * MP * 64 * 2) + 255) & ~(i64)255;
    i64 s0b = (((i64)gsz * MP * 512 * 2) + 255) & ~(i64)255;
    u16* f_xe0 = (u16*)(R + s0a);
    u16* f_gi0 = (u16*)(R + s0a + s0b);

    auto cvt = [&](const float* s, u16* dst, int Rr, int C, int Rp, int Cp) {
        i64 tot = (i64)Rp * Cp;
        convert_pad<<<(int)((tot + 255) / 256), 256, 0, stream>>>(s, dst, Rr, C, Rp, Cp);
    };
    auto gemmN = [&](const u16* A, const u16* B, const float* bias, void* C,
                     int gx, int Nc, int K, int Mstore, int ldc, int mode) {
        int NYT = (Nc + 127) / 128;
        dim3 g(gx * NYT);
        if (mode == 0)      gemm_bf16mfma<0><<<g, 256, 0, stream>>>(A, B, bias, C, K, Mstore, Nc, ldc, gx, NYT);
        else if (mode == 1) gemm_bf16mfma<1><<<g, 256, 0, stream>>>(A, B, bias, C, K, Mstore, Nc, ldc, gx, NYT);
        else if (mode == 2) gemm_bf16mfma<2><<<g, 256, 0, stream>>>(A, B, bias, C, K, Mstore, Nc, ldc, gx, NYT);
        else                gemm_bf16mfma<3><<<g, 256, 0, stream>>>(A, B, bias, C, K, Mstore, Nc, ldc, gx, NYT);
    };

    cvt(Wih0, wih0b, 1536, 512, 1536, 512);
    cvt(Whh0, whh0b, 1536, 512, 1536, 512);
    cvt(Wih1, wih1b, 768, 256, 768, 256);
    cvt(Whh1, whh1b, 768, 256, 768, 256);
    cvt(W_emb0, we0b, 512, 48, 512, 64);
    cvt(W_emb1, we1b, 256, 24, 256, 64);
    cvt(Wpred0, wp0b, 48, 512, 128, 512);
    cvt(Wpred1, wp1b, 24, 256, 128, 256);
    pmat_fill_bf<<<(int)(((i64)768 * 512 + 255) / 256), 256, 0, stream>>>(pos0, chan0, f_pm0, 2, 512, 768);
    pmat_fill_bf<<<(int)(((i64)1408 * 256 + 255) / 256), 256, 0, stream>>>(pos1, chan1, f_pm1, 4, 256, 1408);

    // ================= layer 0: d=512, s=48, 15 steps =================
    {
        i64 n = (i64)MP * 512;
        zero_bf<<<(int)((n / 2 + 255) / 256), 256, 0, stream>>>(f_mirA, n);
    }
    for (int t0 = 0; t0 < 15;) {
        int g = 15 - t0 < gsz ? 15 - t0 : gsz;
        i64 tot = (i64)g * MP * 64;
        seg_gather_bf<<<(int)((tot + 255) / 256), 256, 0, stream>>>(x, f_seg0, t0, g, 48, 64);
        gemmN(f_seg0, we0b, b_emb0, f_xe0, g * 81, 512, 64, g * MP, 512, 2);
        // hoisted xe·Wih: gi0 = relu(xe)·Wih0^T + bih0, FRAGMENT layout
        gemmN(f_xe0, wih0b, bih0, f_gi0, g * 81, 1536, 512, g * MP, 1536, 3);
        for (int s = 0; s < g; ++s) {
            int tg = t0 + s;
            const u16* Asrc = (tg & 1) ? f_mirB : f_mirA;
            u16* Adst = (tg & 1) ? f_mirA : f_mirB;
            gru_step_h<512><<<dim3(162, 8), 256, 0, stream>>>(
                f_gi0 + (i64)s * MP * 1536, Asrc, whh0b, bhh0, Adst);
        }
        t0 += g;
    }
    // decoder 0 (t=14 wrote mirB; h_old read from mirB inside gru_dec)
    gemmN(f_pm0, wih0b, bih0, f_gidec, 6, 1536, 512, 642, 1536, 1);
    gru_dec<512, 2><<<dim3(81 * 8), 256, 0, stream>>>(
        f_mirB, whh0b, bhh0, f_gidec, f_hy);
    gemmN(f_hy, wp0b, bpred0, f_y0, 161, 48, 512, 2 * NB, 48, 0);

    // ================= layer 1: d=256, s=24, 60 steps (4 xe segments) =========
    {
        i64 n = (i64)MP * 256;
        zero_bf<<<(int)((n / 2 + 255) / 256), 256, 0, stream>>>(f_mirA, n);
    }
    {
        i64 tot = (i64)4 * MP * 64;
        seg_gather_bf<<<(int)((tot + 255) / 256), 256, 0, stream>>>(x, f_seg1, 0, 4, 24, 64);
    }
    gemmN(f_seg1, we1b, b_emb1, f_xe1, 324, 256, 64, 4 * MP, 256, 2);
    // precompute gi for the 4 distinct xe segments, FRAGMENT layout (mode 3)
    gemmN(f_xe1, wih1b, bih1, f_gi1, 324, 768, 256, 4 * MP, 768, 3);
    for (int t = 0; t < 60; ++t) {
        const u16* Asrc = (t & 1) ? f_mirB : f_mirA;
        u16* Adst = (t & 1) ? f_mirA : f_mirB;
        gru_step_h<256><<<dim3(162, 4), 256, 0, stream>>>(
            f_gi1 + (i64)(t & 3) * MP * 768, Asrc, whh1b, bhh1, Adst);
    }
    // decoder 1 (t=59 wrote mirA; h_old read from mirA inside gru_dec)
    gemmN(f_pm1, wih1b, bih1, f_gidec, 11, 768, 256, 1284, 768, 1);
    gru_dec<256, 4><<<dim3(81 * 4), 256, 0, stream>>>(
        f_mirA, whh1b, bhh1, f_gidec, f_hy);
    gemmN(f_hy, wp1b, bpred1, f_y1, 321, 24, 256, 4 * NB, 24, 0);

    // ================= combine =================
    out_kernel<<<(BATCH_ * PRED_ * ENC_ + 255) / 256, 256, 0, stream>>>(x, f_y0, f_y1, out);
}

// Round 12
// 2015.597 us; speedup vs baseline: 1.1886x; 1.1886x over previous
//
#include <hip/hip_runtime.h>
#include <math.h>

// Hierarchical RNN — round 20: base = round-17 (verified 2174us; r19's gi0
// hoist reverted). New: layers 0 and 1 are data-independent, so their steps
// t=0..14 run in ONE fused launch each (grid (162,12): y<8 = layer-0 two-phase
// body, y>=8 = layer-1 h-only body) — the latency-bound layer-1 step hides
// under the layer-0 step. Layer-1 keeps its own mirror pair; gi1 moved to the
// fixed region so it persists through the layer-0 loop.

#define NB     10272
#define MP     10368
#define ENC_   321
#define SEQ_   720
#define PRED_  96
#define BATCH_ 32

typedef long long i64;
typedef unsigned short u16;
typedef unsigned int u32;
using bf16x8 = __attribute__((ext_vector_type(8))) short;
using f32x4  = __attribute__((ext_vector_type(4))) float;
using u16x4  = __attribute__((ext_vector_type(4))) unsigned short;

#define AS1 __attribute__((address_space(1)))
#define AS3 __attribute__((address_space(3)))
#define GLOAD16(g, l) __builtin_amdgcn_global_load_lds((const AS1 void*)(g), (AS3 void*)(l), 16, 0, 0)
#define MFMA16(a, b, c) __builtin_amdgcn_mfma_f32_16x16x32_bf16(a, b, c, 0, 0, 0)

__device__ __forceinline__ float bf2f(u16 u) {
    union { u32 i; float f; } v; v.i = ((u32)u) << 16; return v.f;
}
__device__ __forceinline__ u16 f2bf(float f) {
    union { float f; u32 i; } v; v.f = f;
    return (u16)((v.i + 0x7fff + ((v.i >> 16) & 1)) >> 16);
}
__device__ __forceinline__ float sigf(float x) {
    x = fminf(fmaxf(x, -30.f), 30.f);
    return 1.f / (1.f + __expf(-x));
}
__device__ __forceinline__ float tanhfast(float x) {
    x = fminf(fmaxf(x, -15.f), 15.f);
    float e = __expf(2.f * x);
    return (e - 1.f) / (e + 1.f);
}
// XCD-aware flat-grid swizzle for the big GEMMs
__device__ __forceinline__ void swz(int idx, int NXT, int NYT, int& mt, int& nt) {
    int per = NYT * 8;
    int grp = idx / per;
    int base = grp * 8;
    int mg = NXT - base; if (mg > 8) mg = 8;
    int rem = idx - grp * per;
    mt = base + rem % mg;
    nt = rem / mg;
}

// ---------------------------------------------------------------- small utils
__global__ __launch_bounds__(256) void zero_bf(u16* __restrict__ b, i64 n) {
    i64 i = (i64)blockIdx.x * 256 + threadIdx.x;
    i64 n2 = n >> 1;
    if (i < n2) ((u32*)b)[i] = 0;
}

__global__ __launch_bounds__(256) void convert_pad(const float* __restrict__ src,
                                                   u16* __restrict__ dst,
                                                   int R, int C, int Rp, int Cp) {
    i64 idx = (i64)blockIdx.x * 256 + threadIdx.x;
    i64 total = (i64)Rp * Cp;
    if (idx >= total) return;
    int r = (int)(idx / Cp);
    int c = (int)(idx - (i64)r * Cp);
    dst[idx] = (r < R && c < C) ? f2bf(src[(i64)r * C + c]) : (u16)0;
}

__global__ __launch_bounds__(256) void seg_gather_bf(const float* __restrict__ x,
                                                     u16* __restrict__ dst,
                                                     int t0, int T, int s, int Kp) {
    i64 idx = (i64)blockIdx.x * 256 + threadIdx.x;
    i64 per_t = (i64)MP * Kp;
    i64 total = (i64)T * per_t;
    if (idx >= total) return;
    int t = (int)(idx / per_t);
    i64 rem = idx - (i64)t * per_t;
    int j = (int)(rem / MP);
    int n = (int)(rem - (i64)j * MP);
    float v = 0.f;
    if (n < NB && j < s) {
        int b = n / ENC_, e = n - b * ENC_;
        const float* xb = x + (i64)b * SEQ_ * ENC_ + e;
        v = xb[(i64)((t0 + t) * s + j) * ENC_] - xb[(i64)(SEQ_ - 1) * ENC_];
    }
    dst[((i64)t * MP + n) * Kp + j] = f2bf(v);
}

__global__ __launch_bounds__(256) void pmat_fill_bf(const float* __restrict__ pos,
                                                    const float* __restrict__ chan,
                                                    u16* __restrict__ dst,
                                                    int S, int d, int Rp) {
    i64 idx = (i64)blockIdx.x * 256 + threadIdx.x;
    i64 total = (i64)Rp * d;
    if (idx >= total) return;
    int row = (int)(idx / d);
    int c = (int)(idx - (i64)row * d);
    float v = 0.f;
    if (row < ENC_ * S) {
        int e = row / S, sy = row - e * S;
        int half = d >> 1;
        v = (c < half) ? pos[sy * half + c] : chan[e * half + (c - half)];
    }
    dst[idx] = f2bf(v);
}

__global__ __launch_bounds__(256) void out_kernel(const float* __restrict__ x,
                                                  const float* __restrict__ y0,
                                                  const float* __restrict__ y1,
                                                  float* __restrict__ out) {
    int idx = blockIdx.x * 256 + threadIdx.x;
    const int total = BATCH_ * PRED_ * ENC_;
    if (idx >= total) return;
    int b = idx / (PRED_ * ENC_);
    int r = idx - b * (PRED_ * ENC_);
    int p = r / ENC_;
    int e = r - p * ENC_;
    int n = b * ENC_ + e;
    float sl = x[(i64)b * SEQ_ * ENC_ + (i64)(SEQ_ - 1) * ENC_ + e];
    out[idx] = sl + 0.5f * (y0[(i64)n * PRED_ + p] + y1[(i64)n * PRED_ + p]);
}

// ------------------------------------------------- bf16 MFMA NT GEMM 128x128xK
// MODE: 0 fp32 natural, 1 bf16 natural, 2 bf16+relu, 3 bf16 fragment layout
template<int MODE>
__global__ __launch_bounds__(256) void gemm_bf16mfma(const u16* __restrict__ A,
                                                     const u16* __restrict__ B,
                                                     const float* __restrict__ bias,
                                                     void* __restrict__ Cp,
                                                     int K, int Mstore, int Nstore,
                                                     int ldc, int NXT, int NYT) {
    __shared__ u16 smA[128 * 64];
    __shared__ u16 smB[128 * 64];
    const int tid = threadIdx.x;
    const int w = tid >> 6, l = tid & 63;
    int mt, nt; swz(blockIdx.x, NXT, NYT, mt, nt);
    const int m0 = mt * 128, n0 = nt * 128;
    const int srow = (l >> 3) & 7, pch = l & 7;
    const int cch = pch ^ srow;
    const u16* ga[4]; const u16* gb[4];
#pragma unroll
    for (int r = 0; r < 4; ++r) {
        int seg = r * 4 + w;
        ga[r] = A + (i64)(m0 + seg * 8 + srow) * K + cch * 8;
        gb[r] = B + (i64)(n0 + seg * 8 + srow) * K + cch * 8;
    }
    f32x4 acc[4][4] = {};
    const int lr = l & 15, lg = l >> 4;
    const int wm = (w >> 1) * 64, wn = (w & 1) * 64;
    for (int kk = 0; kk < K; kk += 64) {
#pragma unroll
        for (int r = 0; r < 4; ++r) { GLOAD16(ga[r], smA + (r * 4 + w) * 512); ga[r] += 64; }
#pragma unroll
        for (int r = 0; r < 4; ++r) { GLOAD16(gb[r], smB + (r * 4 + w) * 512); gb[r] += 64; }
        __syncthreads();
#pragma unroll
        for (int s = 0; s < 2; ++s) {
            const int ph = ((s * 4 + lg) ^ (lr & 7)) * 8;
            bf16x8 av[4], bv[4];
#pragma unroll
            for (int i = 0; i < 4; ++i)
                av[i] = *(const bf16x8*)(smA + (wm + i * 16 + lr) * 64 + ph);
#pragma unroll
            for (int j = 0; j < 4; ++j)
                bv[j] = *(const bf16x8*)(smB + (wn + j * 16 + lr) * 64 + ph);
#pragma unroll
            for (int i = 0; i < 4; ++i)
#pragma unroll
                for (int j = 0; j < 4; ++j)
                    acc[i][j] = MFMA16(av[i], bv[j], acc[i][j]);
        }
        __syncthreads();
    }
    if (MODE == 3) {
        // fragment-layout bf16 store: tile (row/16, col/16), elem lane*4+reg.
        const int NCTG = ldc >> 4;
#pragma unroll
        for (int i = 0; i < 4; ++i) {
            int mt16 = (m0 + wm + i * 16) >> 4;
#pragma unroll
            for (int j = 0; j < 4; ++j) {
                int cb = n0 + wn + j * 16;
                if (cb >= Nstore) continue;
                float bs = bias[cb + lr];
                u16x4 sv;
#pragma unroll
                for (int r = 0; r < 4; ++r) sv[r] = f2bf(acc[i][j][r] + bs);
                *(u16x4*)((u16*)Cp + ((i64)mt16 * NCTG + (cb >> 4)) * 256 + l * 4) = sv;
            }
        }
        return;
    }
#pragma unroll
    for (int i = 0; i < 4; ++i) {
        int mbase = m0 + wm + i * 16 + 4 * lg;
#pragma unroll
        for (int j = 0; j < 4; ++j) {
            int c = n0 + wn + j * 16 + lr;
            if (c >= Nstore) continue;
            float bs = bias[c];
#pragma unroll
            for (int r = 0; r < 4; ++r) {
                int mm = mbase + r;
                if (mm < Mstore) {
                    float v = acc[i][j][r] + bs;
                    if (MODE == 2) v = fmaxf(v, 0.f);
                    if (MODE == 0) ((float*)Cp)[(i64)mm * ldc + c] = v;
                    else           ((u16*)Cp)[(i64)mm * ldc + c] = f2bf(v);
                }
            }
        }
    }
}

// ---------------- two-phase encoder step BODY: (xe·Wih + h·Whh) + GRU update.
// 64x64x3 per block; h_old (bf16) from smH side-copy of phase-1 kk==c0 chunk.
template<int D>
__device__ __forceinline__ void gru_step_body(const u16* __restrict__ xe,
                                              const u16* __restrict__ hsrc,
                                              const u16* __restrict__ Wih,
                                              const u16* __restrict__ Whh,
                                              const float* __restrict__ bih,
                                              const float* __restrict__ bhh,
                                              u16* __restrict__ hdst,
                                              int bx, int by,
                                              u16* smA, u16* smB, u16* smH) {
    const int tid = threadIdx.x;
    const int w = tid >> 6, l = tid & 63;
    const int m0 = bx * 64;
    const int c0 = by * 64;
    const int srow = (l >> 3) & 7, pch = l & 7;
    const int cch = pch ^ srow;
    const int lr = l & 15, lg = l >> 4;
    f32x4 aR[4] = {}, aZ[4] = {}, aNI[4] = {}, aNH[4] = {};
#pragma unroll
    for (int phase = 0; phase < 2; ++phase) {
        const u16* Abase = phase ? hsrc : xe;
        const u16* Bbase = phase ? Whh : Wih;
        const u16* ga[2]; const u16* gb[6];
#pragma unroll
        for (int r = 0; r < 2; ++r)
            ga[r] = Abase + (i64)(m0 + (r * 4 + w) * 8 + srow) * D + cch * 8;
#pragma unroll
        for (int q = 0; q < 6; ++q) {
            int gs = q * 4 + w;
            int g = gs >> 3, sp = gs & 7;
            gb[q] = Bbase + (i64)(g * D + c0 + sp * 8 + srow) * D + cch * 8;
        }
        for (int kk = 0; kk < D; kk += 64) {
#pragma unroll
            for (int r = 0; r < 2; ++r) GLOAD16(ga[r], smA + (r * 4 + w) * 512);
            if (phase == 1 && kk == c0) {
#pragma unroll
                for (int r = 0; r < 2; ++r) GLOAD16(ga[r], smH + (r * 4 + w) * 512);
            }
#pragma unroll
            for (int r = 0; r < 2; ++r) ga[r] += 64;
#pragma unroll
            for (int q = 0; q < 6; ++q) { GLOAD16(gb[q], smB + (q * 4 + w) * 512); gb[q] += 64; }
            __syncthreads();
#pragma unroll
            for (int s = 0; s < 2; ++s) {
                const int phs = ((s * 4 + lg) ^ (lr & 7)) * 8;
                bf16x8 av = *(const bf16x8*)(smA + (w * 16 + lr) * 64 + phs);
#pragma unroll
                for (int j = 0; j < 4; ++j) {
                    bf16x8 b0 = *(const bf16x8*)(smB + 0 * 4096 + (j * 16 + lr) * 64 + phs);
                    bf16x8 b1 = *(const bf16x8*)(smB + 1 * 4096 + (j * 16 + lr) * 64 + phs);
                    bf16x8 b2 = *(const bf16x8*)(smB + 2 * 4096 + (j * 16 + lr) * 64 + phs);
                    aR[j] = MFMA16(av, b0, aR[j]);
                    aZ[j] = MFMA16(av, b1, aZ[j]);
                    if (phase == 0)
                        aNI[j] = MFMA16(av, b2, aNI[j]);
                    else
                        aNH[j] = MFMA16(av, b2, aNH[j]);
                }
            }
            __syncthreads();
        }
    }
    const int rowb = m0 + w * 16 + 4 * lg;
#pragma unroll
    for (int j = 0; j < 4; ++j) {
        const int cc = c0 + j * 16 + lr;
        float bR = bih[cc] + bhh[cc];
        float bZ = bih[D + cc] + bhh[D + cc];
        float bNI = bih[2 * D + cc];
        float bNH = bhh[2 * D + cc];
#pragma unroll
        for (int r = 0; r < 4; ++r) {
            const int lrow = w * 16 + 4 * lg + r;
            const int lcol = j * 16 + lr;
            float ho = bf2f(smH[lrow * 64 + ((((lcol >> 3)) ^ (lrow & 7)) << 3) + (lcol & 7)]);
            float rr = sigf(aR[j][r] + bR);
            float zz = sigf(aZ[j][r] + bZ);
            float nn = tanhfast(aNI[j][r] + bNI + rr * (aNH[j][r] + bNH));
            hdst[(i64)(rowb + r) * D + cc] = f2bf((1.f - zz) * nn + zz * ho);
        }
    }
}

// ---------------- h-only encoder step BODY: gh = h·Whh; gi from fragment
// buffer, prefetched under the last MFMA chunk. 64x64x3 per block.
template<int D>
__device__ __forceinline__ void gru_step_h_body(const u16* __restrict__ gi,
                                                const u16* __restrict__ hsrc,
                                                const u16* __restrict__ Whh,
                                                const float* __restrict__ bhh,
                                                u16* __restrict__ hdst,
                                                int bx, int by,
                                                u16* smA, u16* smB, u16* smH) {
    constexpr int NCT = D / 16;
    constexpr int NCTG = 3 * D / 16;
    const int tid = threadIdx.x;
    const int w = tid >> 6, l = tid & 63;
    const int m0 = bx * 64;
    const int c0 = by * 64;
    const int srow = (l >> 3) & 7, pch = l & 7;
    const int cch = pch ^ srow;
    const int lr = l & 15, lg = l >> 4;
    f32x4 aR[4] = {}, aZ[4] = {}, aNH[4] = {};
    const u16* ga[2]; const u16* gb[6];
#pragma unroll
    for (int r = 0; r < 2; ++r)
        ga[r] = hsrc + (i64)(m0 + (r * 4 + w) * 8 + srow) * D + cch * 8;
#pragma unroll
    for (int q = 0; q < 6; ++q) {
        int gs = q * 4 + w;
        int g = gs >> 3, sp = gs & 7;
        gb[q] = Whh + (i64)(g * D + c0 + sp * 8 + srow) * D + cch * 8;
    }
    const int Trow = (m0 >> 4) + w;
    const i64 gbase = (i64)Trow * NCTG * 256 + l * 4;
    u16x4 g0[4], g1[4], g2[4];
    for (int kk = 0; kk < D; kk += 64) {
#pragma unroll
        for (int r = 0; r < 2; ++r) GLOAD16(ga[r], smA + (r * 4 + w) * 512);
        if (kk == c0) {
#pragma unroll
            for (int r = 0; r < 2; ++r) GLOAD16(ga[r], smH + (r * 4 + w) * 512);
        }
#pragma unroll
        for (int r = 0; r < 2; ++r) ga[r] += 64;
#pragma unroll
        for (int q = 0; q < 6; ++q) { GLOAD16(gb[q], smB + (q * 4 + w) * 512); gb[q] += 64; }
        __syncthreads();
        if (kk == D - 64) {
#pragma unroll
            for (int j = 0; j < 4; ++j) {
                const int ct = (c0 >> 4) + j;
                g0[j] = *(const u16x4*)(gi + gbase + (i64)(0 * NCT + ct) * 256);
                g1[j] = *(const u16x4*)(gi + gbase + (i64)(1 * NCT + ct) * 256);
                g2[j] = *(const u16x4*)(gi + gbase + (i64)(2 * NCT + ct) * 256);
            }
        }
#pragma unroll
        for (int s = 0; s < 2; ++s) {
            const int phs = ((s * 4 + lg) ^ (lr & 7)) * 8;
            bf16x8 av = *(const bf16x8*)(smA + (w * 16 + lr) * 64 + phs);
#pragma unroll
            for (int j = 0; j < 4; ++j) {
                bf16x8 b0 = *(const bf16x8*)(smB + 0 * 4096 + (j * 16 + lr) * 64 + phs);
                bf16x8 b1 = *(const bf16x8*)(smB + 1 * 4096 + (j * 16 + lr) * 64 + phs);
                bf16x8 b2 = *(const bf16x8*)(smB + 2 * 4096 + (j * 16 + lr) * 64 + phs);
                aR[j] = MFMA16(av, b0, aR[j]);
                aZ[j] = MFMA16(av, b1, aZ[j]);
                aNH[j] = MFMA16(av, b2, aNH[j]);
            }
        }
        __syncthreads();
    }
    const int rowb = m0 + w * 16 + 4 * lg;
#pragma unroll
    for (int j = 0; j < 4; ++j) {
        const int cc = c0 + j * 16 + lr;
        float bR = bhh[cc];
        float bZ = bhh[D + cc];
        float bNH = bhh[2 * D + cc];
#pragma unroll
        for (int r = 0; r < 4; ++r) {
            const int lrow = w * 16 + 4 * lg + r;
            const int lcol = j * 16 + lr;
            float ho = bf2f(smH[lrow * 64 + ((((lcol >> 3)) ^ (lrow & 7)) << 3) + (lcol & 7)]);
            float rr = sigf(bf2f(g0[j][r]) + aR[j][r] + bR);
            float zz = sigf(bf2f(g1[j][r]) + aZ[j][r] + bZ);
            float nn = tanhfast(bf2f(g2[j][r]) + rr * (aNH[j][r] + bNH));
            hdst[(i64)(rowb + r) * D + cc] = f2bf((1.f - zz) * nn + zz * ho);
        }
    }
}

// standalone layer-1 step (t = 15..59)
template<int D>
__global__ __launch_bounds__(256, 3) void gru_step_h(const u16* __restrict__ gi,
                                                     const u16* __restrict__ hsrc,
                                                     const u16* __restrict__ Whh,
                                                     const float* __restrict__ bhh,
                                                     u16* __restrict__ hdst) {
    __shared__ u16 smA[64 * 64];
    __shared__ u16 smB[3 * 64 * 64];
    __shared__ u16 smH[64 * 64];
    gru_step_h_body<D>(gi, hsrc, Whh, bhh, hdst, blockIdx.x, blockIdx.y, smA, smB, smH);
}

// fused layer-0 + layer-1 step (t = 0..14): y<8 -> layer-0, y>=8 -> layer-1
__global__ __launch_bounds__(256, 3) void gru_step_comb(
    const u16* __restrict__ xe0, const u16* __restrict__ h0src,
    const u16* __restrict__ Wih0, const u16* __restrict__ Whh0,
    const float* __restrict__ bih0, const float* __restrict__ bhh0,
    u16* __restrict__ h0dst,
    const u16* __restrict__ gi1, const u16* __restrict__ h1src,
    const u16* __restrict__ Whh1, const float* __restrict__ bhh1,
    u16* __restrict__ h1dst) {
    __shared__ u16 smA[64 * 64];
    __shared__ u16 smB[3 * 64 * 64];
    __shared__ u16 smH[64 * 64];
    if (blockIdx.y < 8)
        gru_step_body<512>(xe0, h0src, Wih0, Whh0, bih0, bhh0, h0dst,
                           blockIdx.x, blockIdx.y, smA, smB, smH);
    else
        gru_step_h_body<256>(gi1, h1src, Whh1, bhh1, h1dst,
                             blockIdx.x, blockIdx.y - 8, smA, smB, smH);
}

// ---------------------------------------- decoder: fused gh-GEMM + GRU (S>0)
// h_old read directly from the bf16 mirror (= Asrc).
template<int D, int S>
__global__ __launch_bounds__(256) void gru_dec(const u16* __restrict__ Asrc,
                                               const u16* __restrict__ Whh,
                                               const float* __restrict__ bhh,
                                               const u16* __restrict__ gi,
                                               u16* __restrict__ hy) {
    constexpr int NYT = D / 64;
    __shared__ u16 smA[128 * 64];
    __shared__ u16 smB[3 * 64 * 64];
    const int tid = threadIdx.x;
    const int w = tid >> 6, l = tid & 63;
    int mt, nt; swz(blockIdx.x, 81, NYT, mt, nt);
    const int m0 = mt * 128;
    const int c0 = nt * 64;
    const int srow = (l >> 3) & 7, pch = l & 7;
    const int cch = pch ^ srow;
    const u16* ga[4]; const u16* gb[6];
#pragma unroll
    for (int r = 0; r < 4; ++r)
        ga[r] = Asrc + (i64)(m0 + (r * 4 + w) * 8 + srow) * D + cch * 8;
#pragma unroll
    for (int q = 0; q < 6; ++q) {
        int gs = q * 4 + w;
        int g = gs >> 3, sp = gs & 7;
        gb[q] = Whh + (i64)(g * D + c0 + sp * 8 + srow) * D + cch * 8;
    }
    f32x4 acc[3][4][2] = {};
    const int lr = l & 15, lg = l >> 4;
    const int wm = (w >> 1) * 64, wc = (w & 1) * 32;
    for (int kk = 0; kk < D; kk += 64) {
#pragma unroll
        for (int r = 0; r < 4; ++r) { GLOAD16(ga[r], smA + (r * 4 + w) * 512); ga[r] += 64; }
#pragma unroll
        for (int q = 0; q < 6; ++q) { GLOAD16(gb[q], smB + (q * 4 + w) * 512); gb[q] += 64; }
        __syncthreads();
#pragma unroll
        for (int s = 0; s < 2; ++s) {
            const int ph = ((s * 4 + lg) ^ (lr & 7)) * 8;
            bf16x8 av[4], bv[3][2];
#pragma unroll
            for (int i = 0; i < 4; ++i)
                av[i] = *(const bf16x8*)(smA + (wm + i * 16 + lr) * 64 + ph);
#pragma unroll
            for (int g = 0; g < 3; ++g)
#pragma unroll
                for (int j = 0; j < 2; ++j)
                    bv[g][j] = *(const bf16x8*)(smB + g * 4096 + (wc + j * 16 + lr) * 64 + ph);
#pragma unroll
            for (int g = 0; g < 3; ++g)
#pragma unroll
                for (int i = 0; i < 4; ++i)
#pragma unroll
                    for (int j = 0; j < 2; ++j)
                        acc[g][i][j] = MFMA16(av[i], bv[g][j], acc[g][i][j]);
        }
        __syncthreads();
    }
#pragma unroll
    for (int i = 0; i < 4; ++i) {
        const int rowb = m0 + wm + 16 * i + 4 * lg;
        int e0 = rowb % ENC_;
#pragma unroll
        for (int j = 0; j < 2; ++j) {
            const int cc = c0 + wc + 16 * j + lr;
            float b0 = bhh[cc], b1 = bhh[D + cc], b2 = bhh[2 * D + cc];
#pragma unroll
            for (int r = 0; r < 4; ++r) {
                int mm = rowb + r;
                if (mm >= NB) continue;
                int e = e0 + r; if (e >= ENC_) e -= ENC_;
                float ho = bf2f(Asrc[(i64)mm * D + cc]);
                float hr = acc[0][i][j][r] + b0;
                float hz = acc[1][i][j][r] + b1;
                float hn2 = acc[2][i][j][r] + b2;
#pragma unroll
                for (int sy = 0; sy < S; ++sy) {
                    i64 gib = (i64)(e * S + sy) * 3 * D + cc;
                    float rr = sigf(bf2f(gi[gib]) + hr);
                    float zz = sigf(bf2f(gi[gib + D]) + hz);
                    float nn = tanhfast(bf2f(gi[gib + 2 * D]) + rr * hn2);
                    hy[((i64)mm * S + sy) * D + cc] = f2bf((1.f - zz) * nn + zz * ho);
                }
            }
        }
    }
}

// ---------------------------------------------------------------- host
extern "C" void kernel_launch(void* const* d_in, const int* in_sizes, int n_in,
                              void* d_out, int out_size, void* d_ws, size_t ws_size,
                              hipStream_t stream) {
    const float* x      = (const float*)d_in[0];
    const float* W_emb0 = (const float*)d_in[1];
    const float* b_emb0 = (const float*)d_in[2];
    const float* Wih0   = (const float*)d_in[3];
    const float* Whh0   = (const float*)d_in[4];
    const float* bih0   = (const float*)d_in[5];
    const float* bhh0   = (const float*)d_in[6];
    const float* Wpred0 = (const float*)d_in[7];
    const float* bpred0 = (const float*)d_in[8];
    const float* pos0   = (const float*)d_in[9];
    const float* chan0  = (const float*)d_in[10];
    const float* W_emb1 = (const float*)d_in[11];
    const float* b_emb1 = (const float*)d_in[12];
    const float* Wih1   = (const float*)d_in[13];
    const float* Whh1   = (const float*)d_in[14];
    const float* bih1   = (const float*)d_in[15];
    const float* bhh1   = (const float*)d_in[16];
    const float* Wpred1 = (const float*)d_in[17];
    const float* bpred1 = (const float*)d_in[18];
    const float* pos1   = (const float*)d_in[19];
    const float* chan1  = (const float*)d_in[20];
    float* out = (float*)d_out;

    i64 off = 0;
    char* base = (char*)d_ws;
    auto alloc = [&](i64 bytes) -> void* {
        void* p = base + off; off += (bytes + 255) & ~(i64)255; return p;
    };
    u16*   f_mirA  = (u16*)  alloc((i64)MP * 512 * 2);   // layer-0 mirrors
    u16*   f_mirB  = (u16*)  alloc((i64)MP * 512 * 2);
    u16*   f_m1A   = (u16*)  alloc((i64)MP * 256 * 2);   // layer-1 mirrors
    u16*   f_m1B   = (u16*)  alloc((i64)MP * 256 * 2);
    u16*   wih0b   = (u16*)  alloc((i64)1536 * 512 * 2);
    u16*   whh0b   = (u16*)  alloc((i64)1536 * 512 * 2);
    u16*   wih1b   = (u16*)  alloc((i64)768 * 256 * 2);
    u16*   whh1b   = (u16*)  alloc((i64)768 * 256 * 2);
    u16*   we0b    = (u16*)  alloc((i64)512 * 64 * 2);
    u16*   we1b    = (u16*)  alloc((i64)256 * 64 * 2);
    u16*   wp0b    = (u16*)  alloc((i64)128 * 512 * 2);
    u16*   wp1b    = (u16*)  alloc((i64)128 * 256 * 2);
    u16*   f_pm0   = (u16*)  alloc((i64)768 * 512 * 2);
    u16*   f_pm1   = (u16*)  alloc((i64)1408 * 256 * 2);
    u16*   f_gidec = (u16*)  alloc((i64)768 * 1536 * 2);
    u16*   f_hy    = (u16*)  alloc((i64)4 * NB * 256 * 2);
    float* f_y0    = (float*)alloc((i64)NB * 96 * 4);
    float* f_y1    = (float*)alloc((i64)NB * 96 * 4);
    u16*   f_gi1   = (u16*)  alloc((i64)4 * MP * 768 * 2);  // persists through L0 loop
    i64 fixed = off;

    // shared region R (phase-exclusive):
    //   pre-phase: seg1 | xe1 (consumed before layer-0 loop starts)
    //   layer-0 loop: seg0 | xe0 (groups of gsz steps)
    char* R = base + fixed;
    i64 a1 = (((i64)4 * MP * 64 * 2) + 255) & ~(i64)255;    // seg1
    i64 a2 = (i64)4 * MP * 256 * 2;                         // xe1
    i64 R1 = a1 + a2;
    u16* f_seg1 = (u16*)R;
    u16* f_xe1  = (u16*)(R + a1);
    int gsz = 1;
    {
        const int cand[4] = {15, 5, 3, 2};
        for (int ii = 0; ii < 4; ++ii) {
            i64 need = (i64)cand[ii] * MP * (64 + 512) * 2 + 2 * 256;
            i64 tot = fixed + (need > R1 ? need : R1);
            if (tot <= (i64)ws_size) { gsz = cand[ii]; break; }
        }
    }
    u16* f_seg0 = (u16*)R;
    i64 s1 = (((i64)gsz * MP * 64 * 2) + 255) & ~(i64)255;
    u16* f_xe0 = (u16*)(R + s1);

    auto cvt = [&](const float* s, u16* dst, int Rr, int C, int Rp, int Cp) {
        i64 tot = (i64)Rp * Cp;
        convert_pad<<<(int)((tot + 255) / 256), 256, 0, stream>>>(s, dst, Rr, C, Rp, Cp);
    };
    auto gemmN = [&](const u16* A, const u16* B, const float* bias, void* C,
                     int gx, int Nc, int K, int Mstore, int ldc, int mode) {
        int NYT = (Nc + 127) / 128;
        dim3 g(gx * NYT);
        if (mode == 0)      gemm_bf16mfma<0><<<g, 256, 0, stream>>>(A, B, bias, C, K, Mstore, Nc, ldc, gx, NYT);
        else if (mode == 1) gemm_bf16mfma<1><<<g, 256, 0, stream>>>(A, B, bias, C, K, Mstore, Nc, ldc, gx, NYT);
        else if (mode == 2) gemm_bf16mfma<2><<<g, 256, 0, stream>>>(A, B, bias, C, K, Mstore, Nc, ldc, gx, NYT);
        else                gemm_bf16mfma<3><<<g, 256, 0, stream>>>(A, B, bias, C, K, Mstore, Nc, ldc, gx, NYT);
    };

    cvt(Wih0, wih0b, 1536, 512, 1536, 512);
    cvt(Whh0, whh0b, 1536, 512, 1536, 512);
    cvt(Wih1, wih1b, 768, 256, 768, 256);
    cvt(Whh1, whh1b, 768, 256, 768, 256);
    cvt(W_emb0, we0b, 512, 48, 512, 64);
    cvt(W_emb1, we1b, 256, 24, 256, 64);
    cvt(Wpred0, wp0b, 48, 512, 128, 512);
    cvt(Wpred1, wp1b, 24, 256, 128, 256);
    pmat_fill_bf<<<(int)(((i64)768 * 512 + 255) / 256), 256, 0, stream>>>(pos0, chan0, f_pm0, 2, 512, 768);
    pmat_fill_bf<<<(int)(((i64)1408 * 256 + 255) / 256), 256, 0, stream>>>(pos1, chan1, f_pm1, 4, 256, 1408);

    // ---- layer-1 pre-phase: seg1 -> xe1 -> gi1 (fragment layout, fixed region)
    {
        i64 n0 = (i64)MP * 512;
        zero_bf<<<(int)((n0 / 2 + 255) / 256), 256, 0, stream>>>(f_mirA, n0);
        i64 n1 = (i64)MP * 256;
        zero_bf<<<(int)((n1 / 2 + 255) / 256), 256, 0, stream>>>(f_m1A, n1);
        i64 tot = (i64)4 * MP * 64;
        seg_gather_bf<<<(int)((tot + 255) / 256), 256, 0, stream>>>(x, f_seg1, 0, 4, 24, 64);
    }
    gemmN(f_seg1, we1b, b_emb1, f_xe1, 324, 256, 64, 4 * MP, 256, 2);
    gemmN(f_xe1, wih1b, bih1, f_gi1, 324, 768, 256, 4 * MP, 768, 3);

    // ---- fused steps t=0..14: layer-0 two-phase + layer-1 h-only in one launch
    for (int t0 = 0; t0 < 15;) {
        int g = 15 - t0 < gsz ? 15 - t0 : gsz;
        i64 tot = (i64)g * MP * 64;
        seg_gather_bf<<<(int)((tot + 255) / 256), 256, 0, stream>>>(x, f_seg0, t0, g, 48, 64);
        gemmN(f_seg0, we0b, b_emb0, f_xe0, g * 81, 512, 64, g * MP, 512, 2);
        for (int s = 0; s < g; ++s) {
            int tg = t0 + s;
            const u16* A0s = (tg & 1) ? f_mirB : f_mirA;
            u16* A0d = (tg & 1) ? f_mirA : f_mirB;
            const u16* A1s = (tg & 1) ? f_m1B : f_m1A;
            u16* A1d = (tg & 1) ? f_m1A : f_m1B;
            gru_step_comb<<<dim3(162, 12), 256, 0, stream>>>(
                f_xe0 + (i64)s * MP * 512, A0s, wih0b, whh0b, bih0, bhh0, A0d,
                f_gi1 + (i64)(tg & 3) * MP * 768, A1s, whh1b, bhh1, A1d);
        }
        t0 += g;
    }
    // ---- remaining layer-1 steps t=15..59
    for (int t = 15; t < 60; ++t) {
        const u16* A1s = (t & 1) ? f_m1B : f_m1A;
        u16* A1d = (t & 1) ? f_m1A : f_m1B;
        gru_step_h<256><<<dim3(162, 4), 256, 0, stream>>>(
            f_gi1 + (i64)(t & 3) * MP * 768, A1s, whh1b, bhh1, A1d);
    }

    // ---- decoders + predictions
    gemmN(f_pm0, wih0b, bih0, f_gidec, 6, 1536, 512, 642, 1536, 1);
    gru_dec<512, 2><<<dim3(81 * 8), 256, 0, stream>>>(
        f_mirB, whh0b, bhh0, f_gidec, f_hy);
    gemmN(f_hy, wp0b, bpred0, f_y0, 161, 48, 512, 2 * NB, 48, 0);

    gemmN(f_pm1, wih1b, bih1, f_gidec, 11, 768, 256, 1284, 768, 1);
    gru_dec<256, 4><<<dim3(81 * 4), 256, 0, stream>>>(
        f_m1A, whh1b, bhh1, f_gidec, f_hy);
    gemmN(f_hy, wp1b, bpred1, f_y1, 321, 24, 256, 4 * NB, 24, 0);

    // ---- combine
    out_kernel<<<(BATCH_ * PRED_ * ENC_ + 255) / 256, 256, 0, stream>>>(x, f_y0, f_y1, out);
}